// Round 2
// baseline (3199.785 us; speedup 1.0000x reference)
//
#include <hip/hip_runtime.h>
#include <hip/hip_bf16.h>
#include <stdint.h>

#define LL 2
#define HH 8
#define EE 512
#define FFD 2048
#define BB 8
#define SS 1024

typedef unsigned short u16;
typedef __attribute__((ext_vector_type(8))) short bf16x8;
typedef __attribute__((ext_vector_type(4))) float f32x4;
typedef __attribute__((ext_vector_type(4))) int int4v;

__device__ __forceinline__ u16 f2bf(float f){
  union { float f; unsigned u; } c; c.f = f;
  unsigned r = (c.u + 0x7FFFu + ((c.u >> 16) & 1u)) >> 16;
  return (u16)r;
}

// ---------------------------------------------------------------------------
// Generic 128x128 tile GEMM, C = A(MxK) * B(NxK)^T, bf16 in / f32 accum.
// Unified power-of-2 stride decomposition:
//   A elem addr = AsMHi*(m>>10) + AsMLo*(m&1023) + AsH*(k>>9) + (k&511)
//   B elem addr = BsNHi*(n>>9)  + BsNLo*(n&511)  + BsH*(k>>9) + (k&511)
//   O elem addr = OsMHi*(m>>10) + OsMLo*(m&1023) + OsNHi*(n>>9) + OsNLo*(n&511)
// EP: 0=f32 out*scale (+causal tile skip), 1=bf16 out+bias, 2=bf16 out (+causal
// K-limit), 3=f32 out+bias+resid, 4=bf16 out+bias+relu
// ---------------------------------------------------------------------------
struct GP {
  const u16* A; const u16* B;
  const float* bias; const float* resid;
  void* out;
  long AsMHi, AsMLo, AsH;
  long BsNHi, BsNLo, BsH;
  long Abatch, Bbatch, Obatch;
  long OsMHi, OsMLo, OsNHi, OsNLo;
  int M, N, K, causal;
  float scale;
};

template<int EP>
__global__ __launch_bounds__(256, 2) void k_gemm(GP p){
  const int tilesN = p.N >> 7;
  const int m0 = (blockIdx.x / tilesN) << 7;
  const int n0 = (blockIdx.x % tilesN) << 7;
  if (EP == 0 && p.causal && n0 > m0) return;   // fully-masked causal tile
  const long bb = blockIdx.y;
  const u16* __restrict__ Ag = p.A + bb * p.Abatch;
  const u16* __restrict__ Bg = p.B + bb * p.Bbatch;

  __shared__ __align__(16) u16 As[128 * 64];
  __shared__ __align__(16) u16 Bs[128 * 64];
  char* AsB = (char*)As;
  char* BsB = (char*)Bs;

  const int t = threadIdx.x;
  const int lane = t & 63;
  const int wv = t >> 6;
  const int wr = (wv >> 1) << 6;   // wave row origin (0/64)
  const int wc = (wv & 1) << 6;    // wave col origin (0/64)

  // staging: 2 threads per tile row, 64B (4x16B chunks) each
  const int srow  = t >> 1;
  const int skoff = (t & 1) << 5;  // 0 or 32 elements into the 64-wide K slab
  const int gmA = m0 + srow;
  const long abase = (long)(gmA >> 10) * p.AsMHi + (long)(gmA & 1023) * p.AsMLo;
  const int gnB = n0 + srow;
  const long bbase = (long)(gnB >> 9) * p.BsNHi + (long)(gnB & 511) * p.BsNLo;
  const int swz = (srow & 7) << 4;
  int wAddr[4];
  #pragma unroll
  for (int q = 0; q < 4; ++q)
    wAddr[q] = srow * 128 + (((skoff << 1) + (q << 4)) ^ swz);

  int Klim = p.K;
  if (EP == 2 && p.causal) { int kl = m0 + 128; Klim = kl < p.K ? kl : p.K; }

  f32x4 acc[4][4];
  #pragma unroll
  for (int a = 0; a < 4; ++a)
    #pragma unroll
    for (int b = 0; b < 4; ++b)
      acc[a][b] = (f32x4){0.f, 0.f, 0.f, 0.f};

  int4v ra[4], rb[4];
  #pragma unroll
  for (int q = 0; q < 4; ++q){
    int k = skoff + (q << 3);
    ra[q] = *reinterpret_cast<const int4v*>(Ag + abase + (long)(k >> 9) * p.AsH + (k & 511));
    rb[q] = *reinterpret_cast<const int4v*>(Bg + bbase + (long)(k >> 9) * p.BsH + (k & 511));
  }

  for (int k0 = 0; k0 < Klim; ){
    __syncthreads();
    #pragma unroll
    for (int q = 0; q < 4; ++q){
      *reinterpret_cast<int4v*>(AsB + wAddr[q]) = ra[q];
      *reinterpret_cast<int4v*>(BsB + wAddr[q]) = rb[q];
    }
    __syncthreads();
    const int kn = k0 + 64;
    if (kn < Klim){
      #pragma unroll
      for (int q = 0; q < 4; ++q){
        int k = kn + skoff + (q << 3);
        ra[q] = *reinterpret_cast<const int4v*>(Ag + abase + (long)(k >> 9) * p.AsH + (k & 511));
        rb[q] = *reinterpret_cast<const int4v*>(Bg + bbase + (long)(k >> 9) * p.BsH + (k & 511));
      }
    }
    #pragma unroll
    for (int kk = 0; kk < 2; ++kk){
      bf16x8 af[4], bv[4];
      #pragma unroll
      for (int mi = 0; mi < 4; ++mi){
        int row = wr + (mi << 4) + (lane & 15);
        int bc = ((kk << 6) + ((lane >> 4) << 4)) ^ ((row & 7) << 4);
        af[mi] = *reinterpret_cast<const bf16x8*>(AsB + row * 128 + bc);
      }
      #pragma unroll
      for (int ni = 0; ni < 4; ++ni){
        int row = wc + (ni << 4) + (lane & 15);
        int bc = ((kk << 6) + ((lane >> 4) << 4)) ^ ((row & 7) << 4);
        bv[ni] = *reinterpret_cast<const bf16x8*>(BsB + row * 128 + bc);
      }
      #pragma unroll
      for (int mi = 0; mi < 4; ++mi)
        #pragma unroll
        for (int ni = 0; ni < 4; ++ni)
          acc[mi][ni] = __builtin_amdgcn_mfma_f32_16x16x32_bf16(af[mi], bv[ni], acc[mi][ni], 0, 0, 0);
    }
    k0 = kn;
  }

  // epilogue: D row=(lane>>4)*4+i, col=lane&15
  const int cm = (lane >> 4) << 2;
  const int cn = lane & 15;
  float biasv[4];
  if (EP == 1 || EP == 3 || EP == 4){
    #pragma unroll
    for (int ni = 0; ni < 4; ++ni)
      biasv[ni] = p.bias[n0 + wc + (ni << 4) + cn];
  }
  #pragma unroll
  for (int mi = 0; mi < 4; ++mi){
    #pragma unroll
    for (int i = 0; i < 4; ++i){
      const int m = m0 + wr + (mi << 4) + cm + i;
      const long ob = bb * p.Obatch + (long)(m >> 10) * p.OsMHi + (long)(m & 1023) * p.OsMLo;
      #pragma unroll
      for (int ni = 0; ni < 4; ++ni){
        const int n = n0 + wc + (ni << 4) + cn;
        const long oa = ob + (long)(n >> 9) * p.OsNHi + (long)(n & 511) * p.OsNLo;
        float v = acc[mi][ni][i];
        if (EP == 0) ((float*)p.out)[oa] = v * p.scale;
        else if (EP == 1) ((u16*)p.out)[oa] = f2bf(v + biasv[ni]);
        else if (EP == 2) ((u16*)p.out)[oa] = f2bf(v);
        else if (EP == 3) ((float*)p.out)[oa] = v + biasv[ni] + p.resid[oa];
        else { float r = v + biasv[ni]; ((u16*)p.out)[oa] = f2bf(r > 0.f ? r : 0.f); }
      }
    }
  }
}

// ---------------------------------------------------------------------------
__global__ void k_cvt(const float* __restrict__ s, u16* __restrict__ d, int n){
  const int i = (blockIdx.x * 256 + threadIdx.x) << 3;
  if (i >= n) return;
  f32x4 a = *reinterpret_cast<const f32x4*>(s + i);
  f32x4 b = *reinterpret_cast<const f32x4*>(s + i + 4);
  union { u16 us[8]; int4v v; } u;
  #pragma unroll
  for (int j = 0; j < 4; ++j){ u.us[j] = f2bf(a[j]); u.us[4 + j] = f2bf(b[j]); }
  *reinterpret_cast<int4v*>(d + i) = u.v;
}

__global__ void k_init(const float* __restrict__ x, float* __restrict__ xf,
                       u16* __restrict__ xb, int n){
  const int i = (blockIdx.x * 256 + threadIdx.x) << 3;
  if (i >= n) return;
  f32x4 a = *reinterpret_cast<const f32x4*>(x + i);
  f32x4 b = *reinterpret_cast<const f32x4*>(x + i + 4);
  *reinterpret_cast<f32x4*>(xf + i) = a;
  *reinterpret_cast<f32x4*>(xf + i + 4) = b;
  union { u16 us[8]; int4v v; } u;
  #pragma unroll
  for (int j = 0; j < 4; ++j){ u.us[j] = f2bf(a[j]); u.us[4 + j] = f2bf(b[j]); }
  *reinterpret_cast<int4v*>(xb + i) = u.v;
}

// row softmax over scores[0..q], zero-fill the rest; P *= alpha[h]
// pbase = global (b*H+h) index of local pair 0
__global__ __launch_bounds__(256) void k_softmax(const float* __restrict__ scores,
                                                 u16* __restrict__ P,
                                                 const float* __restrict__ alphas,
                                                 int pbase){
  __shared__ float buf[SS];
  __shared__ float red[4];
  const long row = blockIdx.x;
  const int q = (int)(row & (SS - 1));
  const int h = (pbase + (int)(row >> 10)) & (HH - 1);
  const float* src = scores + row * SS;
  u16* dst = P + row * SS;
  const int t = threadIdx.x;
  float lm = -1e30f;
  for (int i = t; i < SS; i += 256){
    float v = (i <= q) ? src[i] : -1e30f;
    buf[i] = v;
    lm = fmaxf(lm, v);
  }
  for (int o = 32; o; o >>= 1) lm = fmaxf(lm, __shfl_xor(lm, o));
  if ((t & 63) == 0) red[t >> 6] = lm;
  __syncthreads();
  const float m = fmaxf(fmaxf(red[0], red[1]), fmaxf(red[2], red[3]));
  float ls = 0.f;
  for (int i = t; i < SS; i += 256){
    float e = exp2f((buf[i] - m) * 1.4426950408889634f);
    buf[i] = e;
    ls += e;
  }
  for (int o = 32; o; o >>= 1) ls += __shfl_xor(ls, o);
  __syncthreads();
  if ((t & 63) == 0) red[t >> 6] = ls;
  __syncthreads();
  const float s = red[0] + red[1] + red[2] + red[3];
  const float inv = alphas[h] / s;
  for (int i = t; i < SS; i += 256) dst[i] = f2bf(buf[i] * inv);
}

// per-pair (S,E) -> (E,S), 64x64 bf16 tiles; blockIdx.y = local pair
__global__ __launch_bounds__(256) void k_transpose(const u16* __restrict__ v,
                                                   u16* __restrict__ vt){
  const long bh = blockIdx.y;
  const int ts = blockIdx.x >> 3;
  const int td = blockIdx.x & 7;
  const u16* src = v + bh * (long)(SS * EE) + (long)(ts * 64) * EE + td * 64;
  u16* dst = vt + bh * (long)(SS * EE) + (long)(td * 64) * SS + ts * 64;
  __shared__ __align__(16) u16 tl[64][80];
  const int t = threadIdx.x;
  #pragma unroll
  for (int it = 0; it < 2; ++it){
    int id = t + it * 256;
    int r = id >> 3, c = (id & 7) << 3;
    *reinterpret_cast<int4v*>(&tl[r][c]) =
        *reinterpret_cast<const int4v*>(src + (long)r * EE + c);
  }
  __syncthreads();
  #pragma unroll
  for (int it = 0; it < 2; ++it){
    int id = t + it * 256;
    int r = id >> 3, c = (id & 7) << 3;
    union { u16 us[8]; int4v v; } u;
    #pragma unroll
    for (int j = 0; j < 8; ++j) u.us[j] = tl[c + j][r];
    *reinterpret_cast<int4v*>(dst + (long)r * SS + c) = u.v;
  }
}

__global__ __launch_bounds__(256) void k_ln(const float* __restrict__ src,
                                            const float* __restrict__ g,
                                            const float* __restrict__ b,
                                            float* __restrict__ fdst,
                                            u16* __restrict__ bdst){
  const long row = blockIdx.x;
  const float* x = src + row * EE;
  const int t = threadIdx.x;
  float v0 = x[t], v1 = x[t + 256];
  float s = v0 + v1;
  for (int o = 32; o; o >>= 1) s += __shfl_xor(s, o);
  __shared__ float red[4];
  if ((t & 63) == 0) red[t >> 6] = s;
  __syncthreads();
  const float mean = (red[0] + red[1] + red[2] + red[3]) * (1.0f / EE);
  float d0 = v0 - mean, d1 = v1 - mean;
  float vs = d0 * d0 + d1 * d1;
  for (int o = 32; o; o >>= 1) vs += __shfl_xor(vs, o);
  __syncthreads();
  if ((t & 63) == 0) red[t >> 6] = vs;
  __syncthreads();
  const float var = (red[0] + red[1] + red[2] + red[3]) * (1.0f / EE);
  const float rstd = rsqrtf(var + 1e-5f);
  float o0 = d0 * rstd * g[t] + b[t];
  float o1 = d1 * rstd * g[t + 256] + b[t + 256];
  fdst[row * EE + t] = o0;
  fdst[row * EE + t + 256] = o1;
  bdst[row * EE + t] = f2bf(o0);
  bdst[row * EE + t + 256] = f2bf(o1);
}

__global__ void k_sumbo(const float* __restrict__ bo, float* __restrict__ dst){
  const int o = blockIdx.x * 256 + threadIdx.x;
  if (o >= EE) return;
  float s = 0.f;
  #pragma unroll
  for (int h = 0; h < HH; ++h) s += bo[h * EE + o];
  dst[o] = s;
}

// ---------------------------------------------------------------------------
static inline void gemm_launch(int EP, const GP& p, int batch, hipStream_t st){
  dim3 g((unsigned)((p.M >> 7) * (p.N >> 7)), (unsigned)batch);
  switch (EP){
    case 0: k_gemm<0><<<g, 256, 0, st>>>(p); break;
    case 1: k_gemm<1><<<g, 256, 0, st>>>(p); break;
    case 2: k_gemm<2><<<g, 256, 0, st>>>(p); break;
    case 3: k_gemm<3><<<g, 256, 0, st>>>(p); break;
    case 4: k_gemm<4><<<g, 256, 0, st>>>(p); break;
  }
}

extern "C" void kernel_launch(void* const* d_in, const int* in_sizes, int n_in,
                              void* d_out, int out_size, void* d_ws, size_t ws_size,
                              hipStream_t stream){
  const float* x    = (const float*)d_in[0];
  const float* Wq   = (const float*)d_in[1];
  const float* bq   = (const float*)d_in[2];
  const float* Wk   = (const float*)d_in[3];
  const float* bk   = (const float*)d_in[4];
  const float* Wv   = (const float*)d_in[5];
  const float* bv   = (const float*)d_in[6];
  const float* Wo   = (const float*)d_in[7];
  const float* bo   = (const float*)d_in[8];
  const float* alph = (const float*)d_in[9];
  const float* ln1g = (const float*)d_in[10];
  const float* ln1b = (const float*)d_in[11];
  const float* W1   = (const float*)d_in[12];
  const float* b1   = (const float*)d_in[13];
  const float* W2   = (const float*)d_in[14];
  const float* b2   = (const float*)d_in[15];
  const float* ln2g = (const float*)d_in[16];
  const float* ln2b = (const float*)d_in[17];
  float* out = (float*)d_out;

  const size_t nWh = (size_t)HH * EE * EE;        // 2,097,152 (per-layer Wq/k/v/o)
  const size_t nWf = (size_t)FFD * EE;            // 1,048,576 (per-layer W1/W2)
  const size_t nX  = (size_t)BB * SS * EE;        // 4,194,304
  const size_t nQ  = (size_t)BB * HH * SS * EE;   // 33,554,432
  const size_t nPairV  = (size_t)SS * EE;         // vt elems per pair
  const size_t nPairS  = (size_t)SS * SS;         // scores elems per pair

  // fixed footprint (bytes, with per-take 256B pad slack folded in)
  const size_t fixedB = 2*nWh*4 + 2*nWf*2        // per-layer bf16 weights (20 MiB)
                      + 4*nX + 2*nX              // xf + xb (24 MiB)
                      + 3 * 2*nQ                 // q,k,v bf16 (192 MiB)
                      + 4096 + 16*256;           // bo_sum + pad slack
  const size_t perPairB = 2*nPairV + 4*nPairS + 2*nPairS;  // 7,340,032
  int CH = 64;
  while (CH > 1 && fixedB + (size_t)CH * perPairB > ws_size) CH >>= 1;
  const int NC = 64 / CH;

  char* w = (char*)d_ws;
  size_t off = 0;
  auto take = [&](size_t bytes) -> char* {
    char* p = w + off;
    off += (bytes + 255) & ~(size_t)255;
    return p;
  };

  u16* wqb = (u16*)take(2 * nWh);
  u16* wkb = (u16*)take(2 * nWh);
  u16* wvb = (u16*)take(2 * nWh);
  u16* wob = (u16*)take(2 * nWh);
  u16* w1b = (u16*)take(2 * nWf);
  u16* w2b = (u16*)take(2 * nWf);
  float* xf = (float*)take(4 * nX);
  u16* xb   = (u16*)take(2 * nX);
  u16* qb   = (u16*)take(2 * nQ);
  u16* kb   = (u16*)take(2 * nQ);
  u16* vb   = (u16*)take(2 * nQ);
  float* bo_sum = (float*)take(4 * EE);
  u16* vtb  = (u16*)take(2 * nPairV * CH);
  float* sc = (float*)take(4 * nPairS * CH);
  u16* pbuf = (u16*)take(2 * nPairS * CH);
  float* tmp = out;        // d_out doubles as the pre-LN f32 buffer (16 MiB)
  u16* hid = qb;           // alias: q dead after scores GEMMs

  auto cvt = [&](const float* s, u16* d, size_t n){
    k_cvt<<<dim3((unsigned)(n / 2048)), 256, 0, stream>>>(s, d, (int)n);
  };
  k_init<<<dim3((unsigned)(nX / 2048)), 256, 0, stream>>>(x, xf, xb, (int)nX);

  for (int i = 0; i < LL; ++i){
    // ---- convert this layer's weights to bf16 ----
    cvt(Wq + i * nWh, wqb, nWh); cvt(Wk + i * nWh, wkb, nWh);
    cvt(Wv + i * nWh, wvb, nWh); cvt(Wo + i * nWh, wob, nWh);
    cvt(W1 + i * nWf, w1b, nWf); cvt(W2 + i * nWf, w2b, nWf);

    // ---- QKV projections: x(8192x512) @ W^T -> (B,H,S,E) bf16 ----
    GP p{};
    p.AsMHi = (long)1024 * EE; p.AsMLo = EE; p.AsH = 0;
    p.BsNHi = (long)EE * EE;   p.BsNLo = EE; p.BsH = 0;
    p.Abatch = p.Bbatch = p.Obatch = 0;
    p.OsMHi = (long)HH * SS * EE; p.OsMLo = EE; p.OsNHi = (long)SS * EE; p.OsNLo = 1;
    p.M = BB * SS; p.N = HH * EE; p.K = EE;
    p.A = xb; p.scale = 1.f; p.causal = 0; p.resid = nullptr;
    p.B = wqb; p.bias = bq + (size_t)i * HH * EE; p.out = qb;
    gemm_launch(1, p, 1, stream);
    p.B = wkb; p.bias = bk + (size_t)i * HH * EE; p.out = kb;
    gemm_launch(1, p, 1, stream);
    p.B = wvb; p.bias = bv + (size_t)i * HH * EE; p.out = vb;
    gemm_launch(1, p, 1, stream);

    // ---- attention, chunked over (b,h) pairs to fit ws ----
    for (int c = 0; c < NC; ++c){
      const size_t pbase = (size_t)c * CH;
      const size_t poff = pbase * nPairV;

      k_transpose<<<dim3(128, CH), 256, 0, stream>>>(vb + poff, vtb);

      GP ps{};
      ps.A = qb + poff; ps.B = kb + poff; ps.out = sc;
      ps.AsMHi = 0; ps.AsMLo = EE; ps.AsH = 0;
      ps.BsNHi = (long)512 * EE; ps.BsNLo = EE; ps.BsH = 0;
      ps.Abatch = (long)SS * EE; ps.Bbatch = (long)SS * EE; ps.Obatch = (long)SS * SS;
      ps.OsMHi = 0; ps.OsMLo = SS; ps.OsNHi = 512; ps.OsNLo = 1;
      ps.M = SS; ps.N = SS; ps.K = EE;
      ps.scale = 0.044194173824159216f; ps.causal = 1;
      ps.bias = nullptr; ps.resid = nullptr;
      gemm_launch(0, ps, CH, stream);

      k_softmax<<<dim3(CH * SS), 256, 0, stream>>>(sc, pbuf, alph, (int)pbase);

      GP pv{};
      pv.A = pbuf; pv.B = vtb; pv.out = vb + poff;   // overwrite V chunk (vt holds copy)
      pv.AsMHi = 0; pv.AsMLo = SS; pv.AsH = 512;
      pv.BsNHi = 0; pv.BsNLo = SS; pv.BsH = 512;
      pv.Abatch = (long)SS * SS; pv.Bbatch = (long)EE * SS; pv.Obatch = (long)SS * EE;
      pv.OsMHi = 0; pv.OsMLo = EE; pv.OsNHi = 0; pv.OsNLo = 1;
      pv.M = SS; pv.N = EE; pv.K = SS; pv.causal = 1;
      pv.scale = 1.f; pv.bias = nullptr; pv.resid = nullptr;
      gemm_launch(2, pv, CH, stream);
    }

    // ---- sum_h bo ----
    k_sumbo<<<dim3(2), 256, 0, stream>>>(bo + (size_t)i * HH * EE, bo_sum);

    // ---- attn_out = ao(gathered over heads) @ Wo^T + bias + resid ----
    GP pw{};
    pw.A = vb; pw.B = wob; pw.out = tmp;
    pw.AsMHi = (long)HH * SS * EE; pw.AsMLo = EE; pw.AsH = (long)SS * EE;
    pw.BsNHi = 0; pw.BsNLo = EE; pw.BsH = (long)EE * EE;
    pw.Abatch = pw.Bbatch = pw.Obatch = 0;
    pw.OsMHi = (long)SS * EE; pw.OsMLo = EE; pw.OsNHi = 0; pw.OsNLo = 1;
    pw.M = BB * SS; pw.N = EE; pw.K = HH * EE;
    pw.bias = bo_sum; pw.resid = xf; pw.scale = 1.f; pw.causal = 0;
    gemm_launch(3, pw, 1, stream);

    // ---- LN1 -> xf, xb ----
    k_ln<<<dim3(BB * SS), 256, 0, stream>>>(tmp, ln1g + (size_t)i * EE,
                                            ln1b + (size_t)i * EE, xf, xb);

    // ---- FFN up: relu(x @ W1^T + b1) -> hid bf16 ----
    GP p1{};
    p1.A = xb; p1.B = w1b; p1.out = hid;
    p1.AsMHi = (long)1024 * EE; p1.AsMLo = EE; p1.AsH = 0;
    p1.BsNHi = (long)512 * EE; p1.BsNLo = EE; p1.BsH = 0;
    p1.Abatch = p1.Bbatch = p1.Obatch = 0;
    p1.OsMHi = (long)1024 * FFD; p1.OsMLo = FFD; p1.OsNHi = 512; p1.OsNLo = 1;
    p1.M = BB * SS; p1.N = FFD; p1.K = EE;
    p1.bias = b1 + (size_t)i * FFD; p1.resid = nullptr; p1.scale = 1.f; p1.causal = 0;
    gemm_launch(4, p1, 1, stream);

    // ---- FFN down: hid @ W2^T + b2 + resid -> tmp ----
    GP p2{};
    p2.A = hid; p2.B = w2b; p2.out = tmp;
    p2.AsMHi = (long)1024 * FFD; p2.AsMLo = FFD; p2.AsH = 512;
    p2.BsNHi = 0; p2.BsNLo = FFD; p2.BsH = 512;
    p2.Abatch = p2.Bbatch = p2.Obatch = 0;
    p2.OsMHi = (long)SS * EE; p2.OsMLo = EE; p2.OsNHi = 0; p2.OsNLo = 1;
    p2.M = BB * SS; p2.N = EE; p2.K = FFD;
    p2.bias = b2 + (size_t)i * EE; p2.resid = xf; p2.scale = 1.f; p2.causal = 0;
    gemm_launch(3, p2, 1, stream);

    // ---- LN2 -> (final? d_out : xf), xb ----
    float* fdst = (i == LL - 1) ? out : xf;
    k_ln<<<dim3(BB * SS), 256, 0, stream>>>(tmp, ln2g + (size_t)i * EE,
                                            ln2b + (size_t)i * EE, fdst, xb);
  }
}

// Round 3
// 2087.192 us; speedup vs baseline: 1.5331x; 1.5331x over previous
//
#include <hip/hip_runtime.h>
#include <hip/hip_bf16.h>
#include <stdint.h>

#define LL 2
#define HH 8
#define EE 512
#define FFD 2048
#define BB 8
#define SS 1024

typedef unsigned short u16;
typedef __attribute__((ext_vector_type(8))) short bf16x8;
typedef __attribute__((ext_vector_type(4))) float f32x4;
typedef __attribute__((ext_vector_type(4))) int int4v;

__device__ __forceinline__ u16 f2bf(float f){
  union { float f; unsigned u; } c; c.f = f;
  unsigned r = (c.u + 0x7FFFu + ((c.u >> 16) & 1u)) >> 16;
  return (u16)r;
}

// ---------------------------------------------------------------------------
// Generic 128x128 tile GEMM, C = A(MxK) * B(NxK)^T, bf16 in / f32 accum.
// Staging: global_load_lds width=16, linear LDS dest, PRE-SWIZZLED global
// source (XOR involution on the k-slab), swizzled ds_read (unchanged).
//   A elem addr = AsMHi*(m>>10) + AsMLo*(m&1023) + AsH*(k>>9) + (k&511)
//   B elem addr = BsNHi*(n>>9)  + BsNLo*(n&511)  + BsH*(k>>9) + (k&511)
//   O elem addr = OsMHi*(m>>10) + OsMLo*(m&1023) + OsNHi*(n>>9) + OsNLo*(n&511)
// EP: 0=bf16 out*scale (+causal tile skip), 1=bf16 out+bias, 2=bf16 out
// (+causal K-limit), 3=f32 out+bias+resid, 4=bf16 out+bias+relu
// ---------------------------------------------------------------------------
struct GP {
  const u16* A; const u16* B;
  const float* bias; const float* resid;
  void* out;
  long AsMHi, AsMLo, AsH;
  long BsNHi, BsNLo, BsH;
  long Abatch, Bbatch, Obatch;
  long OsMHi, OsMLo, OsNHi, OsNLo;
  int M, N, K, causal;
  float scale;
};

template<int EP>
__global__ __launch_bounds__(256, 3) void k_gemm(GP p){
  const int tilesN = p.N >> 7;
  const int m0 = (blockIdx.x / tilesN) << 7;
  const int n0 = (blockIdx.x % tilesN) << 7;
  if (EP == 0 && p.causal && n0 > m0) return;   // fully-masked causal tile
  const long bb = blockIdx.y;
  const u16* __restrict__ Ag = p.A + bb * p.Abatch;
  const u16* __restrict__ Bg = p.B + bb * p.Bbatch;

  __shared__ __align__(16) u16 As[128 * 64];
  __shared__ __align__(16) u16 Bs[128 * 64];
  char* AsB = (char*)As;
  char* BsB = (char*)Bs;

  const int t = threadIdx.x;
  const int lane = t & 63;
  const int wv = t >> 6;
  const int wr = (wv >> 1) << 6;   // wave row origin (0/64)
  const int wc = (wv & 1) << 6;    // wave col origin (0/64)

  // staging geometry: wave wv, instr j -> LDS rows (wv*4+j)*8 .. +8
  // lane -> row +(lane>>3), 16B slot (lane&7). Global k pre-XORed so that
  // LDS byte c of row r holds global slab byte c ^ ((r&7)<<4).
  long aoff[4], boff[4];
  #pragma unroll
  for (int j = 0; j < 4; ++j){
    const int r = ((wv << 2) + j) * 8 + (lane >> 3);
    const int kx = ((lane & 7) << 3) ^ ((r & 7) << 3);
    const int gm = m0 + r;
    aoff[j] = (long)(gm >> 10) * p.AsMHi + (long)(gm & 1023) * p.AsMLo + kx;
    const int gn = n0 + r;
    boff[j] = (long)(gn >> 9) * p.BsNHi + (long)(gn & 511) * p.BsNLo + kx;
  }

  int Klim = p.K;
  if (EP == 2 && p.causal) { int kl = m0 + 128; Klim = kl < p.K ? kl : p.K; }

  f32x4 acc[4][4];
  #pragma unroll
  for (int a = 0; a < 4; ++a)
    #pragma unroll
    for (int b = 0; b < 4; ++b)
      acc[a][b] = (f32x4){0.f, 0.f, 0.f, 0.f};

  for (int k0 = 0; k0 < Klim; k0 += 64){
    const long ka = (long)(k0 >> 9) * p.AsH + (k0 & 511);
    const long kb = (long)(k0 >> 9) * p.BsH + (k0 & 511);
    __syncthreads();   // LDS free (previous MFMA phase done)
    #pragma unroll
    for (int j = 0; j < 4; ++j){
      const int ldsOff = (((wv << 2) + j) << 9);   // u16 elems, 1KB per instr
      __builtin_amdgcn_global_load_lds(
          (const __attribute__((address_space(1))) void*)(Ag + aoff[j] + ka),
          (__attribute__((address_space(3))) void*)(As + ldsOff), 16, 0, 0);
      __builtin_amdgcn_global_load_lds(
          (const __attribute__((address_space(1))) void*)(Bg + boff[j] + kb),
          (__attribute__((address_space(3))) void*)(Bs + ldsOff), 16, 0, 0);
    }
    __syncthreads();   // vmcnt(0) drain -> tile resident
    #pragma unroll
    for (int kk = 0; kk < 2; ++kk){
      bf16x8 af[4], bv[4];
      #pragma unroll
      for (int mi = 0; mi < 4; ++mi){
        int row = wr + (mi << 4) + (lane & 15);
        int bc = ((kk << 6) + ((lane >> 4) << 4)) ^ ((row & 7) << 4);
        af[mi] = *reinterpret_cast<const bf16x8*>(AsB + row * 128 + bc);
      }
      #pragma unroll
      for (int ni = 0; ni < 4; ++ni){
        int row = wc + (ni << 4) + (lane & 15);
        int bc = ((kk << 6) + ((lane >> 4) << 4)) ^ ((row & 7) << 4);
        bv[ni] = *reinterpret_cast<const bf16x8*>(BsB + row * 128 + bc);
      }
      #pragma unroll
      for (int mi = 0; mi < 4; ++mi)
        #pragma unroll
        for (int ni = 0; ni < 4; ++ni)
          acc[mi][ni] = __builtin_amdgcn_mfma_f32_16x16x32_bf16(af[mi], bv[ni], acc[mi][ni], 0, 0, 0);
    }
  }

  // epilogue: D row=(lane>>4)*4+i, col=lane&15
  const int cm = (lane >> 4) << 2;
  const int cn = lane & 15;
  float biasv[4];
  if (EP == 1 || EP == 3 || EP == 4){
    #pragma unroll
    for (int ni = 0; ni < 4; ++ni)
      biasv[ni] = p.bias[n0 + wc + (ni << 4) + cn];
  }
  #pragma unroll
  for (int mi = 0; mi < 4; ++mi){
    #pragma unroll
    for (int i = 0; i < 4; ++i){
      const int m = m0 + wr + (mi << 4) + cm + i;
      const long ob = bb * p.Obatch + (long)(m >> 10) * p.OsMHi + (long)(m & 1023) * p.OsMLo;
      #pragma unroll
      for (int ni = 0; ni < 4; ++ni){
        const int n = n0 + wc + (ni << 4) + cn;
        const long oa = ob + (long)(n >> 9) * p.OsNHi + (long)(n & 511) * p.OsNLo;
        float v = acc[mi][ni][i];
        if (EP == 0) ((u16*)p.out)[oa] = f2bf(v * p.scale);
        else if (EP == 1) ((u16*)p.out)[oa] = f2bf(v + biasv[ni]);
        else if (EP == 2) ((u16*)p.out)[oa] = f2bf(v);
        else if (EP == 3) ((float*)p.out)[oa] = v + biasv[ni] + p.resid[oa];
        else { float r = v + biasv[ni]; ((u16*)p.out)[oa] = f2bf(r > 0.f ? r : 0.f); }
      }
    }
  }
}

// ---------------------------------------------------------------------------
__global__ void k_cvt(const float* __restrict__ s, u16* __restrict__ d, int n){
  const int i = (blockIdx.x * 256 + threadIdx.x) << 3;
  if (i >= n) return;
  f32x4 a = *reinterpret_cast<const f32x4*>(s + i);
  f32x4 b = *reinterpret_cast<const f32x4*>(s + i + 4);
  union { u16 us[8]; int4v v; } u;
  #pragma unroll
  for (int j = 0; j < 4; ++j){ u.us[j] = f2bf(a[j]); u.us[4 + j] = f2bf(b[j]); }
  *reinterpret_cast<int4v*>(d + i) = u.v;
}

__global__ void k_init(const float* __restrict__ x, float* __restrict__ xf,
                       u16* __restrict__ xb, int n){
  const int i = (blockIdx.x * 256 + threadIdx.x) << 3;
  if (i >= n) return;
  f32x4 a = *reinterpret_cast<const f32x4*>(x + i);
  f32x4 b = *reinterpret_cast<const f32x4*>(x + i + 4);
  *reinterpret_cast<f32x4*>(xf + i) = a;
  *reinterpret_cast<f32x4*>(xf + i + 4) = b;
  union { u16 us[8]; int4v v; } u;
  #pragma unroll
  for (int j = 0; j < 4; ++j){ u.us[j] = f2bf(a[j]); u.us[4 + j] = f2bf(b[j]); }
  *reinterpret_cast<int4v*>(xb + i) = u.v;
}

// in-place row softmax over bf16 scores[0..q]; zero beyond q; P *= alpha[h]
__global__ __launch_bounds__(128) void k_softmax(u16* __restrict__ sp,
                                                 const float* __restrict__ alphas,
                                                 int pbase){
  const long row = blockIdx.x;
  const int q = (int)(row & (SS - 1));
  const int h = (pbase + (int)(row >> 10)) & (HH - 1);
  u16* rp = sp + row * SS;
  const int t = threadIdx.x;
  const int i0 = t << 3;
  bf16x8 rv = *reinterpret_cast<const bf16x8*>(rp + i0);
  float v[8];
  float lm = -1e30f;
  #pragma unroll
  for (int j = 0; j < 8; ++j){
    union { unsigned u; float f; } c; c.u = ((unsigned)(u16)rv[j]) << 16;
    v[j] = (i0 + j <= q) ? c.f : -1e30f;
    lm = fmaxf(lm, v[j]);
  }
  #pragma unroll
  for (int o = 32; o; o >>= 1) lm = fmaxf(lm, __shfl_xor(lm, o));
  __shared__ float red[2];
  if ((t & 63) == 0) red[t >> 6] = lm;
  __syncthreads();
  const float m = fmaxf(red[0], red[1]);
  float ls = 0.f;
  #pragma unroll
  for (int j = 0; j < 8; ++j){
    float e = exp2f((v[j] - m) * 1.4426950408889634f);
    e = (i0 + j <= q) ? e : 0.f;
    v[j] = e; ls += e;
  }
  #pragma unroll
  for (int o = 32; o; o >>= 1) ls += __shfl_xor(ls, o);
  __syncthreads();
  if ((t & 63) == 0) red[t >> 6] = ls;
  __syncthreads();
  const float inv = alphas[h] / (red[0] + red[1]);
  union { u16 us[8]; bf16x8 v8; } o8;
  #pragma unroll
  for (int j = 0; j < 8; ++j) o8.us[j] = f2bf(v[j] * inv);
  *reinterpret_cast<bf16x8*>(rp + i0) = o8.v8;
}

// per-pair (S,E) -> (E,S), 64x64 bf16 tiles; blockIdx.y = local pair
__global__ __launch_bounds__(256) void k_transpose(const u16* __restrict__ v,
                                                   u16* __restrict__ vt){
  const long bh = blockIdx.y;
  const int ts = blockIdx.x >> 3;
  const int td = blockIdx.x & 7;
  const u16* src = v + bh * (long)(SS * EE) + (long)(ts * 64) * EE + td * 64;
  u16* dst = vt + bh * (long)(SS * EE) + (long)(td * 64) * SS + ts * 64;
  __shared__ __align__(16) u16 tl[64][80];
  const int t = threadIdx.x;
  #pragma unroll
  for (int it = 0; it < 2; ++it){
    int id = t + it * 256;
    int r = id >> 3, c = (id & 7) << 3;
    *reinterpret_cast<int4v*>(&tl[r][c]) =
        *reinterpret_cast<const int4v*>(src + (long)r * EE + c);
  }
  __syncthreads();
  #pragma unroll
  for (int it = 0; it < 2; ++it){
    int id = t + it * 256;
    int r = id >> 3, c = (id & 7) << 3;
    union { u16 us[8]; int4v v; } u;
    #pragma unroll
    for (int j = 0; j < 8; ++j) u.us[j] = tl[c + j][r];
    *reinterpret_cast<int4v*>(dst + (long)r * SS + c) = u.v;
  }
}

__global__ __launch_bounds__(256) void k_ln(const float* __restrict__ src,
                                            const float* __restrict__ g,
                                            const float* __restrict__ b,
                                            float* __restrict__ fdst,
                                            u16* __restrict__ bdst){
  const long row = blockIdx.x;
  const float* x = src + row * EE;
  const int t = threadIdx.x;
  float v0 = x[t], v1 = x[t + 256];
  float s = v0 + v1;
  for (int o = 32; o; o >>= 1) s += __shfl_xor(s, o);
  __shared__ float red[4];
  if ((t & 63) == 0) red[t >> 6] = s;
  __syncthreads();
  const float mean = (red[0] + red[1] + red[2] + red[3]) * (1.0f / EE);
  float d0 = v0 - mean, d1 = v1 - mean;
  float vs = d0 * d0 + d1 * d1;
  for (int o = 32; o; o >>= 1) vs += __shfl_xor(vs, o);
  __syncthreads();
  if ((t & 63) == 0) red[t >> 6] = vs;
  __syncthreads();
  const float var = (red[0] + red[1] + red[2] + red[3]) * (1.0f / EE);
  const float rstd = rsqrtf(var + 1e-5f);
  float o0 = d0 * rstd * g[t] + b[t];
  float o1 = d1 * rstd * g[t + 256] + b[t + 256];
  fdst[row * EE + t] = o0;
  fdst[row * EE + t + 256] = o1;
  bdst[row * EE + t] = f2bf(o0);
  bdst[row * EE + t + 256] = f2bf(o1);
}

__global__ void k_sumbo(const float* __restrict__ bo, float* __restrict__ dst){
  const int o = blockIdx.x * 256 + threadIdx.x;
  if (o >= EE) return;
  float s = 0.f;
  #pragma unroll
  for (int h = 0; h < HH; ++h) s += bo[h * EE + o];
  dst[o] = s;
}

// ---------------------------------------------------------------------------
static inline void gemm_launch(int EP, const GP& p, int batch, hipStream_t st){
  dim3 g((unsigned)((p.M >> 7) * (p.N >> 7)), (unsigned)batch);
  switch (EP){
    case 0: k_gemm<0><<<g, 256, 0, st>>>(p); break;
    case 1: k_gemm<1><<<g, 256, 0, st>>>(p); break;
    case 2: k_gemm<2><<<g, 256, 0, st>>>(p); break;
    case 3: k_gemm<3><<<g, 256, 0, st>>>(p); break;
    case 4: k_gemm<4><<<g, 256, 0, st>>>(p); break;
  }
}

extern "C" void kernel_launch(void* const* d_in, const int* in_sizes, int n_in,
                              void* d_out, int out_size, void* d_ws, size_t ws_size,
                              hipStream_t stream){
  const float* x    = (const float*)d_in[0];
  const float* Wq   = (const float*)d_in[1];
  const float* bq   = (const float*)d_in[2];
  const float* Wk   = (const float*)d_in[3];
  const float* bk   = (const float*)d_in[4];
  const float* Wv   = (const float*)d_in[5];
  const float* bv   = (const float*)d_in[6];
  const float* Wo   = (const float*)d_in[7];
  const float* bo   = (const float*)d_in[8];
  const float* alph = (const float*)d_in[9];
  const float* ln1g = (const float*)d_in[10];
  const float* ln1b = (const float*)d_in[11];
  const float* W1   = (const float*)d_in[12];
  const float* b1   = (const float*)d_in[13];
  const float* W2   = (const float*)d_in[14];
  const float* b2   = (const float*)d_in[15];
  const float* ln2g = (const float*)d_in[16];
  const float* ln2b = (const float*)d_in[17];
  float* out = (float*)d_out;

  const size_t nWh = (size_t)HH * EE * EE;        // 2,097,152 (per-layer Wq/k/v/o)
  const size_t nWf = (size_t)FFD * EE;            // 1,048,576 (per-layer W1/W2)
  const size_t nX  = (size_t)BB * SS * EE;        // 4,194,304
  const size_t nQ  = (size_t)BB * HH * SS * EE;   // 33,554,432
  const size_t nPairV  = (size_t)SS * EE;         // vt elems per pair
  const size_t nPairS  = (size_t)SS * SS;         // scores elems per pair

  const size_t fixedB = 2*nWh*4 + 2*nWf*2        // per-layer bf16 weights
                      + 4*nX + 2*nX              // xf + xb
                      + 3 * 2*nQ                 // q,k,v bf16
                      + 4096 + 32*256;           // bo_sum + pad slack
  const size_t perPairB = 2*nPairS + 2*nPairV;   // bf16 scores (in-place P) + vt
  int CH = 64;
  while (CH > 1 && fixedB + (size_t)CH * perPairB > ws_size) CH >>= 1;
  const int NC = 64 / CH;

  char* w = (char*)d_ws;
  size_t off = 0;
  auto take = [&](size_t bytes) -> char* {
    char* p = w + off;
    off += (bytes + 255) & ~(size_t)255;
    return p;
  };

  u16* wqb = (u16*)take(2 * nWh);
  u16* wkb = (u16*)take(2 * nWh);
  u16* wvb = (u16*)take(2 * nWh);
  u16* wob = (u16*)take(2 * nWh);
  u16* w1b = (u16*)take(2 * nWf);
  u16* w2b = (u16*)take(2 * nWf);
  float* xf = (float*)take(4 * nX);
  u16* xb   = (u16*)take(2 * nX);
  u16* qb   = (u16*)take(2 * nQ);
  u16* kb   = (u16*)take(2 * nQ);
  u16* vb   = (u16*)take(2 * nQ);
  float* bo_sum = (float*)take(4 * EE);
  u16* vtb  = (u16*)take(2 * nPairV * CH);
  u16* sc   = (u16*)take(2 * nPairS * CH);   // bf16 scores, softmax'd in place
  float* tmp = out;        // d_out doubles as the pre-LN f32 buffer
  u16* hid = qb;           // alias: q dead after scores GEMMs

  auto cvt = [&](const float* s, u16* d, size_t n){
    k_cvt<<<dim3((unsigned)(n / 2048)), 256, 0, stream>>>(s, d, (int)n);
  };
  k_init<<<dim3((unsigned)(nX / 2048)), 256, 0, stream>>>(x, xf, xb, (int)nX);

  for (int i = 0; i < LL; ++i){
    // ---- convert this layer's weights to bf16 ----
    cvt(Wq + i * nWh, wqb, nWh); cvt(Wk + i * nWh, wkb, nWh);
    cvt(Wv + i * nWh, wvb, nWh); cvt(Wo + i * nWh, wob, nWh);
    cvt(W1 + i * nWf, w1b, nWf); cvt(W2 + i * nWf, w2b, nWf);

    // ---- QKV projections: x(8192x512) @ W^T -> (B,H,S,E) bf16 ----
    GP p{};
    p.AsMHi = (long)1024 * EE; p.AsMLo = EE; p.AsH = 0;
    p.BsNHi = (long)EE * EE;   p.BsNLo = EE; p.BsH = 0;
    p.Abatch = p.Bbatch = p.Obatch = 0;
    p.OsMHi = (long)HH * SS * EE; p.OsMLo = EE; p.OsNHi = (long)SS * EE; p.OsNLo = 1;
    p.M = BB * SS; p.N = HH * EE; p.K = EE;
    p.A = xb; p.scale = 1.f; p.causal = 0; p.resid = nullptr;
    p.B = wqb; p.bias = bq + (size_t)i * HH * EE; p.out = qb;
    gemm_launch(1, p, 1, stream);
    p.B = wkb; p.bias = bk + (size_t)i * HH * EE; p.out = kb;
    gemm_launch(1, p, 1, stream);
    p.B = wvb; p.bias = bv + (size_t)i * HH * EE; p.out = vb;
    gemm_launch(1, p, 1, stream);

    // ---- attention, chunked over (b,h) pairs to fit ws ----
    for (int c = 0; c < NC; ++c){
      const size_t pbase = (size_t)c * CH;
      const size_t poff = pbase * nPairV;

      k_transpose<<<dim3(128, CH), 256, 0, stream>>>(vb + poff, vtb);

      GP ps{};
      ps.A = qb + poff; ps.B = kb + poff; ps.out = sc;
      ps.AsMHi = 0; ps.AsMLo = EE; ps.AsH = 0;
      ps.BsNHi = (long)512 * EE; ps.BsNLo = EE; ps.BsH = 0;
      ps.Abatch = (long)SS * EE; ps.Bbatch = (long)SS * EE; ps.Obatch = (long)SS * SS;
      ps.OsMHi = 0; ps.OsMLo = SS; ps.OsNHi = 512; ps.OsNLo = 1;
      ps.M = SS; ps.N = SS; ps.K = EE;
      ps.scale = 0.044194173824159216f; ps.causal = 1;
      ps.bias = nullptr; ps.resid = nullptr;
      gemm_launch(0, ps, CH, stream);

      k_softmax<<<dim3(CH * SS), 128, 0, stream>>>(sc, alph, (int)pbase);

      GP pv{};
      pv.A = sc; pv.B = vtb; pv.out = vb + poff;   // overwrite V chunk (vt holds copy)
      pv.AsMHi = 0; pv.AsMLo = SS; pv.AsH = 512;
      pv.BsNHi = 0; pv.BsNLo = SS; pv.BsH = 512;
      pv.Abatch = (long)SS * SS; pv.Bbatch = (long)EE * SS; pv.Obatch = (long)SS * EE;
      pv.OsMHi = 0; pv.OsMLo = EE; pv.OsNHi = 0; pv.OsNLo = 1;
      pv.M = SS; pv.N = EE; pv.K = SS; pv.causal = 1;
      pv.scale = 1.f; pv.bias = nullptr; pv.resid = nullptr;
      gemm_launch(2, pv, CH, stream);
    }

    // ---- sum_h bo ----
    k_sumbo<<<dim3(2), 256, 0, stream>>>(bo + (size_t)i * HH * EE, bo_sum);

    // ---- attn_out = ao(gathered over heads) @ Wo^T + bias + resid ----
    GP pw{};
    pw.A = vb; pw.B = wob; pw.out = tmp;
    pw.AsMHi = (long)HH * SS * EE; pw.AsMLo = EE; pw.AsH = (long)SS * EE;
    pw.BsNHi = 0; pw.BsNLo = EE; pw.BsH = (long)EE * EE;
    pw.Abatch = pw.Bbatch = pw.Obatch = 0;
    pw.OsMHi = (long)SS * EE; pw.OsMLo = EE; pw.OsNHi = 0; pw.OsNLo = 1;
    pw.M = BB * SS; pw.N = EE; pw.K = HH * EE;
    pw.bias = bo_sum; pw.resid = xf; pw.scale = 1.f; pw.causal = 0;
    gemm_launch(3, pw, 1, stream);

    // ---- LN1 -> xf, xb ----
    k_ln<<<dim3(BB * SS), 256, 0, stream>>>(tmp, ln1g + (size_t)i * EE,
                                            ln1b + (size_t)i * EE, xf, xb);

    // ---- FFN up: relu(x @ W1^T + b1) -> hid bf16 ----
    GP p1{};
    p1.A = xb; p1.B = w1b; p1.out = hid;
    p1.AsMHi = (long)1024 * EE; p1.AsMLo = EE; p1.AsH = 0;
    p1.BsNHi = (long)512 * EE; p1.BsNLo = EE; p1.BsH = 0;
    p1.Abatch = p1.Bbatch = p1.Obatch = 0;
    p1.OsMHi = (long)1024 * FFD; p1.OsMLo = FFD; p1.OsNHi = 512; p1.OsNLo = 1;
    p1.M = BB * SS; p1.N = FFD; p1.K = EE;
    p1.bias = b1 + (size_t)i * FFD; p1.resid = nullptr; p1.scale = 1.f; p1.causal = 0;
    gemm_launch(4, p1, 1, stream);

    // ---- FFN down: hid @ W2^T + b2 + resid -> tmp ----
    GP p2{};
    p2.A = hid; p2.B = w2b; p2.out = tmp;
    p2.AsMHi = (long)1024 * FFD; p2.AsMLo = FFD; p2.AsH = 512;
    p2.BsNHi = 0; p2.BsNLo = FFD; p2.BsH = 512;
    p2.Abatch = p2.Bbatch = p2.Obatch = 0;
    p2.OsMHi = (long)SS * EE; p2.OsMLo = EE; p2.OsNHi = 0; p2.OsNLo = 1;
    p2.M = BB * SS; p2.N = EE; p2.K = FFD;
    p2.bias = b2 + (size_t)i * EE; p2.resid = xf; p2.scale = 1.f; p2.causal = 0;
    gemm_launch(3, p2, 1, stream);

    // ---- LN2 -> (final? d_out : xf), xb ----
    float* fdst = (i == LL - 1) ? out : xf;
    k_ln<<<dim3(BB * SS), 256, 0, stream>>>(tmp, ln2g + (size_t)i * EE,
                                            ln2b + (size_t)i * EE, fdst, xb);
  }
}